// Round 1
// baseline (10453.677 us; speedup 1.0000x reference)
//
#include <hip/hip_runtime.h>
#include <math.h>

// stacked_rnn: 2-layer LSTM (B=128, T=256, I=150->pad160, H=1024) + FC(60)
// Round 1: per-step MFMA bf16 kernels, fp32 accumulate. ws usage ~37.3 MB.

typedef __bf16 bf16;
typedef __bf16 bf16x8 __attribute__((ext_vector_type(8)));
typedef float floatx4 __attribute__((ext_vector_type(4)));

#define B_   128
#define T_   256
#define H_   1024
#define G4_  4096   // 4*H
#define I_   150
#define KX_  160    // padded I (5 k-steps of 32)
#define C_   60

__device__ __forceinline__ float sigmoidf_(float x) { return 1.f / (1.f + expf(-x)); }

// ---------------- conversion / init kernel (runs every call) ----------------
__global__ __launch_bounds__(256)
void convert_all(const float* __restrict__ x,
                 const float* __restrict__ h1in, const float* __restrict__ c1in,
                 const float* __restrict__ h2in, const float* __restrict__ c2in,
                 const float* __restrict__ Wih1, const float* __restrict__ Whh1,
                 const float* __restrict__ Wih2, const float* __restrict__ Whh2,
                 bf16* __restrict__ w1p, bf16* __restrict__ wh1,
                 bf16* __restrict__ wi2, bf16* __restrict__ wh2,
                 bf16* __restrict__ xb, bf16* __restrict__ h1b0, bf16* __restrict__ h2b0,
                 float* __restrict__ c1, float* __restrict__ c2)
{
    const size_t nW1 = (size_t)G4_ * KX_;       // 655360
    const size_t nWH = (size_t)G4_ * H_;        // 4194304
    const size_t nXB = (size_t)T_ * B_ * KX_;   // 5242880
    const size_t nHC = (size_t)B_ * H_;         // 131072

    size_t idx = (size_t)blockIdx.x * 256 + threadIdx.x;

    if (idx < nW1) {                                 // W_ih1 -> [4096][160] zero-padded
        size_t n = idx / KX_, k = idx - n * KX_;
        w1p[idx] = (k < I_) ? (bf16)Wih1[n * I_ + k] : (bf16)0.f;
        return;
    }
    idx -= nW1;
    if (idx < nWH) { wh1[idx] = (bf16)Whh1[idx]; return; }
    idx -= nWH;
    if (idx < nWH) { wi2[idx] = (bf16)Wih2[idx]; return; }
    idx -= nWH;
    if (idx < nWH) { wh2[idx] = (bf16)Whh2[idx]; return; }
    idx -= nWH;
    if (idx < nXB) {                                 // x [B][T][150] -> xb [T][B][160] bf16
        size_t t = idx / (B_ * KX_);
        size_t r = idx - t * (B_ * KX_);
        size_t b = r / KX_, k = r - b * KX_;
        xb[idx] = (k < I_) ? (bf16)x[(b * T_ + t) * I_ + k] : (bf16)0.f;
        return;
    }
    idx -= nXB;
    if (idx < nHC) { h1b0[idx] = (bf16)h1in[idx]; return; }
    idx -= nHC;
    if (idx < nHC) { h2b0[idx] = (bf16)h2in[idx]; return; }
    idx -= nHC;
    if (idx < nHC) { c1[idx] = c1in[idx]; return; }
    idx -= nHC;
    if (idx < nHC) { c2[idx] = c2in[idx]; return; }
}

// ---------------- one LSTM layer-step ----------------
// gates[b][4H] = A1[b]@W1^T + A2[b]@W2^T + bia + bib ; then i,f,g,o elementwise.
// grid (64, 4): blockIdx.x -> 16 h-cols, blockIdx.y -> 32 batch rows.
// block 256 thr = 4 waves; wave g owns gate group g (cols g*1024 + n0 .. +15).
// Weights row-major [4H][K] (i.e. B^T layout -> B-frag load identical to A-frag, m92 pattern).
template<int NKS1, int LDA1, int LDW1, int NKS2, int LDA2, int LDW2>
__global__ __launch_bounds__(256)
void lstm_step(const bf16* __restrict__ A1, const bf16* __restrict__ W1,
               const bf16* __restrict__ A2, const bf16* __restrict__ W2,
               const float* __restrict__ bia, const float* __restrict__ bib,
               float* __restrict__ cst, bf16* __restrict__ hout)
{
    const int tid  = threadIdx.x;
    const int g    = tid >> 6;          // gate group 0..3 (i,f,g,o)
    const int lane = tid & 63;
    const int lrow = lane & 15;         // tile row/col index
    const int lq   = lane >> 4;         // k-quad 0..3
    const int n0   = blockIdx.x * 16;   // h-col base
    const int r0   = blockIdx.y * 32;   // batch row base
    const int wrow = (g << 10) + n0 + lrow;   // gate column / weight row

    floatx4 acc0 = {0.f, 0.f, 0.f, 0.f};
    floatx4 acc1 = {0.f, 0.f, 0.f, 0.f};

    {   // segment 1
        const bf16* Ab = A1 + (size_t)(r0 + lrow) * LDA1 + lq * 8;
        const bf16* Wb = W1 + (size_t)wrow * LDW1 + lq * 8;
#pragma unroll 8
        for (int ks = 0; ks < NKS1; ++ks) {
            bf16x8 a0 = *(const bf16x8*)(Ab + ks * 32);
            bf16x8 a1 = *(const bf16x8*)(Ab + 16 * LDA1 + ks * 32);
            bf16x8 b  = *(const bf16x8*)(Wb + ks * 32);
            acc0 = __builtin_amdgcn_mfma_f32_16x16x32_bf16(a0, b, acc0, 0, 0, 0);
            acc1 = __builtin_amdgcn_mfma_f32_16x16x32_bf16(a1, b, acc1, 0, 0, 0);
        }
    }
    {   // segment 2
        const bf16* Ab = A2 + (size_t)(r0 + lrow) * LDA2 + lq * 8;
        const bf16* Wb = W2 + (size_t)wrow * LDW2 + lq * 8;
#pragma unroll 8
        for (int ks = 0; ks < NKS2; ++ks) {
            bf16x8 a0 = *(const bf16x8*)(Ab + ks * 32);
            bf16x8 a1 = *(const bf16x8*)(Ab + 16 * LDA2 + ks * 32);
            bf16x8 b  = *(const bf16x8*)(Wb + ks * 32);
            acc0 = __builtin_amdgcn_mfma_f32_16x16x32_bf16(a0, b, acc0, 0, 0, 0);
            acc1 = __builtin_amdgcn_mfma_f32_16x16x32_bf16(a1, b, acc1, 0, 0, 0);
        }
    }

    // stage gates to LDS so each thread can gather i,f,g,o for one (row,col)
    __shared__ float gbuf[4][32][16];
    const float bias = bia[wrow] + bib[wrow];
    // D layout: col = lane&15, row = lq*4 + reg   (m89-verified)
#pragma unroll
    for (int r = 0; r < 4; ++r) {
        gbuf[g][lq * 4 + r][lrow]      = acc0[r] + bias;
        gbuf[g][16 + lq * 4 + r][lrow] = acc1[r] + bias;
    }
    __syncthreads();

#pragma unroll
    for (int it = 0; it < 2; ++it) {
        int idx = tid + it * 256;          // 512 items = 32 rows x 16 cols
        int row = idx >> 4, col = idx & 15;
        float gi = gbuf[0][row][col];
        float gf = gbuf[1][row][col];
        float gg = gbuf[2][row][col];
        float go = gbuf[3][row][col];
        size_t cix = (size_t)(r0 + row) * H_ + n0 + col;
        float c  = cst[cix];
        float cn = sigmoidf_(gf) * c + sigmoidf_(gi) * tanhf(gg);
        cst[cix] = cn;
        hout[cix] = (bf16)(sigmoidf_(go) * tanhf(cn));
    }
}

// ---------------- final FC: out[b][c] = h2[b]@Wfc[c] + bfc[c] ----------------
__global__ __launch_bounds__(256)
void fc_kernel(const bf16* __restrict__ h2, const float* __restrict__ Wfc,
               const float* __restrict__ bfc, float* __restrict__ out)
{
    const int b = blockIdx.x;
    const int w = threadIdx.x >> 6, lane = threadIdx.x & 63;
    for (int c = w; c < C_; c += 4) {
        float acc = 0.f;
        for (int k = lane; k < H_; k += 64)
            acc += (float)h2[(size_t)b * H_ + k] * Wfc[(size_t)c * H_ + k];
#pragma unroll
        for (int off = 32; off; off >>= 1) acc += __shfl_down(acc, off);
        if (lane == 0) out[b * C_ + c] = acc + bfc[c];
    }
}

extern "C" void kernel_launch(void* const* d_in, const int* in_sizes, int n_in,
                              void* d_out, int out_size, void* d_ws, size_t ws_size,
                              hipStream_t stream)
{
    const float* x    = (const float*)d_in[0];
    const float* h1in = (const float*)d_in[1];
    const float* c1in = (const float*)d_in[2];
    const float* h2in = (const float*)d_in[3];
    const float* c2in = (const float*)d_in[4];
    const float* Wih1 = (const float*)d_in[5];
    const float* Whh1 = (const float*)d_in[6];
    const float* bih1 = (const float*)d_in[7];
    const float* bhh1 = (const float*)d_in[8];
    const float* Wih2 = (const float*)d_in[9];
    const float* Whh2 = (const float*)d_in[10];
    const float* bih2 = (const float*)d_in[11];
    const float* bhh2 = (const float*)d_in[12];
    const float* Wfc  = (const float*)d_in[13];
    const float* bfc  = (const float*)d_in[14];
    // d_in[15] = mode (0 = val, no dropout) -- unused

    // workspace carve (total ~37.3 MB)
    char* p = (char*)d_ws;
    bf16* w1p = (bf16*)p; p += (size_t)G4_ * KX_ * 2;
    bf16* wh1 = (bf16*)p; p += (size_t)G4_ * H_ * 2;
    bf16* wi2 = (bf16*)p; p += (size_t)G4_ * H_ * 2;
    bf16* wh2 = (bf16*)p; p += (size_t)G4_ * H_ * 2;
    bf16* xb  = (bf16*)p; p += (size_t)T_ * B_ * KX_ * 2;
    bf16* h1b[2]; h1b[0] = (bf16*)p; p += (size_t)B_ * H_ * 2;
                  h1b[1] = (bf16*)p; p += (size_t)B_ * H_ * 2;
    bf16* h2b[2]; h2b[0] = (bf16*)p; p += (size_t)B_ * H_ * 2;
                  h2b[1] = (bf16*)p; p += (size_t)B_ * H_ * 2;
    float* c1 = (float*)p; p += (size_t)B_ * H_ * 4;
    float* c2 = (float*)p; p += (size_t)B_ * H_ * 4;

    const size_t total = (size_t)G4_ * KX_ + 3 * (size_t)G4_ * H_
                       + (size_t)T_ * B_ * KX_ + 4 * (size_t)B_ * H_;
    const int cblocks = (int)((total + 255) / 256);
    convert_all<<<cblocks, 256, 0, stream>>>(x, h1in, c1in, h2in, c2in,
                                             Wih1, Whh1, Wih2, Whh2,
                                             w1p, wh1, wi2, wh2,
                                             xb, h1b[0], h2b[0], c1, c2);

    dim3 sgrid(64, 4);
    for (int t = 0; t < T_; ++t) {
        const bf16* h1p = h1b[t & 1];       bf16* h1n = h1b[(t + 1) & 1];
        const bf16* h2p = h2b[t & 1];       bf16* h2n = h2b[(t + 1) & 1];
        // layer 1: gates = x_t @ Wih1^T + h1 @ Whh1^T + b
        lstm_step<5, KX_, KX_, 32, H_, H_><<<sgrid, 256, 0, stream>>>(
            xb + (size_t)t * B_ * KX_, w1p, h1p, wh1, bih1, bhh1, c1, h1n);
        // layer 2: gates = h1_new @ Wih2^T + h2 @ Whh2^T + b
        lstm_step<32, H_, H_, 32, H_, H_><<<sgrid, 256, 0, stream>>>(
            h1n, wi2, h2p, wh2, bih2, bhh2, c2, h2n);
    }
    // final h2 is h2b[(255+1)&1] = h2b[0]
    fc_kernel<<<dim3(B_), 256, 0, stream>>>(h2b[0], Wfc, bfc, (float*)d_out);
}